// Round 4
// baseline (271.849 us; speedup 1.0000x reference)
//
#include <hip/hip_runtime.h>
#include <math.h>

#define LL 256
#define DD 64

typedef __attribute__((ext_vector_type(8))) short bf16x8;
typedef __attribute__((ext_vector_type(4))) float f32x4;

static __device__ __forceinline__ unsigned short f2bf(float f) {
    union { float f; unsigned u; } v; v.f = f;
    unsigned r = v.u + 0x7fffu + ((v.u >> 16) & 1u);
    return (unsigned short)(r >> 16);
}
static __device__ __forceinline__ float bf2f(unsigned short h) {
    union { unsigned u; float f; } v; v.u = ((unsigned)h) << 16;
    return v.f;
}

// One block per (b,h,B) group. 512 threads = 8 waves; wave w owns rows [32w,32w+32).
__launch_bounds__(512, 4)
__global__ void fused_attn_mfma(const float* __restrict__ q,
                                const float* __restrict__ k,
                                const float* __restrict__ Wq,
                                const float* __restrict__ bq,
                                const float* __restrict__ Wk,
                                const float* __restrict__ bk,
                                const float* __restrict__ W1,
                                const float* __restrict__ W2a,
                                const float* __restrict__ W2b,
                                float* __restrict__ out)
{
    extern __shared__ char smc[];
    unsigned short* kHi = (unsigned short*)smc;             // [256][64] bf16, swizzled
    unsigned short* kLo = (unsigned short*)(smc + 32768);
    float* sPq  = (float*)(smc + 65536);  // [256] q[i]·Wq
    float* sPk  = sPq + 256;              // [256] k[i]·Wk
    float* sPqk = sPk + 256;              // [256] q[i]·k[i]
    float* sTh  = sPqk + 256;             // [256] theta vector
    float* sSq  = sTh + 256;              // [256] Sigma_q
    float* sSk  = sSq + 256;              // [256] Sigma_k
    float* kwred= sSk + 256;              // [8][64]
    float* kw_s = kwred + 512;            // [64]
    float* sRed = kw_s + 64;              // [8]

    const int tid  = threadIdx.x;
    const int lane = tid & 63;
    const int wid  = tid >> 6;
    const int r16  = lane & 15;
    const int g4   = lane >> 4;
    const int rbase = wid * 32;
    const int gidx = blockIdx.x;
    const size_t gbase = (size_t)gidx * (LL * DD);
    const float* qg = q + gbase;
    const float4* q4 = (const float4*)qg;
    const float4* k4 = (const float4*)(k + gbase);

    // ---- A-operand (q) fragment loads, issued first ----
    float4 aq[2][2][2];
#pragma unroll
    for (int tr = 0; tr < 2; ++tr)
#pragma unroll
        for (int kk = 0; kk < 2; ++kk) {
            const float* p = qg + (rbase + tr * 16 + r16) * DD + kk * 32 + g4 * 8;
            aq[tr][kk][0] = ((const float4*)p)[0];
            aq[tr][kk][1] = ((const float4*)p)[1];
        }

    // ---- loop 1 (dim-major): stage k hi/lo to LDS + kw partials. NO shuffles ----
    const int dc = tid & 15;
    float kw0 = 0.f, kw1 = 0.f, kw2 = 0.f, kw3 = 0.f;
#pragma unroll
    for (int it = 0; it < 8; ++it) {
        const int f = it * 512 + tid;
        const int j = f >> 4;
        const float4 vk = k4[f];
        const int sw = (j & 7) << 4;
        const int boff = j * 128 + ((dc * 8) ^ sw);
        const unsigned short h0 = f2bf(vk.x), h1 = f2bf(vk.y),
                             h2 = f2bf(vk.z), h3 = f2bf(vk.w);
        uint2 hv, lv;
        hv.x = (unsigned)h0 | ((unsigned)h1 << 16);
        hv.y = (unsigned)h2 | ((unsigned)h3 << 16);
        const unsigned short l0 = f2bf(vk.x - bf2f(h0)), l1 = f2bf(vk.y - bf2f(h1)),
                             l2 = f2bf(vk.z - bf2f(h2)), l3 = f2bf(vk.w - bf2f(h3));
        lv.x = (unsigned)l0 | ((unsigned)l1 << 16);
        lv.y = (unsigned)l2 | ((unsigned)l3 << 16);
        *(uint2*)((char*)kHi + boff) = hv;
        *(uint2*)((char*)kLo + boff) = lv;

        const float w1j = W1[j];
        kw0 += w1j * vk.x; kw1 += w1j * vk.y; kw2 += w1j * vk.z; kw3 += w1j * vk.w;
    }

    // ---- loop 2 (row-pair): per-row dots accumulate in registers; 3 shuffles ----
    {
        const int j2 = tid >> 1, h2 = tid & 1;
        float pq = 0.f, pk = 0.f, pqk = 0.f;
#pragma unroll
        for (int it = 0; it < 8; ++it) {
            const int idx = j2 * 16 + h2 * 8 + it;
            const float4 vq = q4[idx];
            const float4 vk = k4[idx];
            const float4 wq4 = ((const float4*)Wq)[h2 * 8 + it];
            const float4 wk4 = ((const float4*)Wk)[h2 * 8 + it];
            pq  += vq.x * wq4.x + vq.y * wq4.y + vq.z * wq4.z + vq.w * wq4.w;
            pk  += vk.x * wk4.x + vk.y * wk4.y + vk.z * wk4.z + vk.w * wk4.w;
            pqk += vq.x * vk.x + vq.y * vk.y + vq.z * vk.z + vq.w * vk.w;
        }
        pq  += __shfl_xor(pq,  1);
        pk  += __shfl_xor(pk,  1);
        pqk += __shfl_xor(pqk, 1);
        if (h2 == 0) { sPq[j2] = pq; sPk[j2] = pk; sPqk[j2] = pqk; }
    }

    // ---- kw cross-lane reduce (8 shuffles, once) ----
    kw0 += __shfl_xor(kw0, 16); kw0 += __shfl_xor(kw0, 32);
    kw1 += __shfl_xor(kw1, 16); kw1 += __shfl_xor(kw1, 32);
    kw2 += __shfl_xor(kw2, 16); kw2 += __shfl_xor(kw2, 32);
    kw3 += __shfl_xor(kw3, 16); kw3 += __shfl_xor(kw3, 32);
    if (lane < 16) {
        float4 kv; kv.x = kw0; kv.y = kw1; kv.z = kw2; kv.w = kw3;
        ((float4*)kwred)[wid * 16 + lane] = kv;
    }

    // ---- convert A frags to bf16 hi/lo ----
    bf16x8 qhi[2][2], qlo[2][2];
#pragma unroll
    for (int tr = 0; tr < 2; ++tr)
#pragma unroll
        for (int kk = 0; kk < 2; ++kk) {
            const float fv[8] = {aq[tr][kk][0].x, aq[tr][kk][0].y, aq[tr][kk][0].z, aq[tr][kk][0].w,
                                 aq[tr][kk][1].x, aq[tr][kk][1].y, aq[tr][kk][1].z, aq[tr][kk][1].w};
#pragma unroll
            for (int e = 0; e < 8; ++e) {
                const unsigned short h = f2bf(fv[e]);
                qhi[tr][kk][e] = (short)h;
                qlo[tr][kk][e] = (short)f2bf(fv[e] - bf2f(h));
            }
        }

    __syncthreads();                                   // B1: staging + kwred + sP* done

    if (tid < 64) {
        float s = 0.f;
#pragma unroll
        for (int w = 0; w < 8; ++w) s += kwred[w * 64 + tid];
        kw_s[tid] = s;
    }

    // ---- MFMA accumulators; chunks interleaved with small phases ----
    f32x4 acc[2][16];
#pragma unroll
    for (int tr = 0; tr < 2; ++tr)
#pragma unroll
        for (int ct = 0; ct < 16; ++ct)
            acc[tr][ct] = (f32x4){0.f, 0.f, 0.f, 0.f};

#define MFMA_CHUNK(CT0, CT1)                                                  \
    _Pragma("unroll")                                                         \
    for (int ct = (CT0); ct < (CT1); ++ct) {                                  \
        const int rowk = ct * 16 + r16;                                       \
        const int sw = (rowk & 7) << 4;                                       \
        const char* ph = (const char*)kHi + rowk * 128;                       \
        const char* pl = (const char*)kLo + rowk * 128;                       \
        const bf16x8 bh0 = *(const bf16x8*)(ph + ((g4 * 16) ^ sw));           \
        const bf16x8 bh1 = *(const bf16x8*)(ph + ((64 + g4 * 16) ^ sw));      \
        const bf16x8 bl0 = *(const bf16x8*)(pl + ((g4 * 16) ^ sw));           \
        const bf16x8 bl1 = *(const bf16x8*)(pl + ((64 + g4 * 16) ^ sw));      \
        _Pragma("unroll")                                                     \
        for (int tr = 0; tr < 2; ++tr) {                                      \
            f32x4 c = acc[tr][ct];                                            \
            c = __builtin_amdgcn_mfma_f32_16x16x32_bf16(qhi[tr][0], bh0, c, 0, 0, 0); \
            c = __builtin_amdgcn_mfma_f32_16x16x32_bf16(qhi[tr][1], bh1, c, 0, 0, 0); \
            c = __builtin_amdgcn_mfma_f32_16x16x32_bf16(qhi[tr][0], bl0, c, 0, 0, 0); \
            c = __builtin_amdgcn_mfma_f32_16x16x32_bf16(qhi[tr][1], bl1, c, 0, 0, 0); \
            c = __builtin_amdgcn_mfma_f32_16x16x32_bf16(qlo[tr][0], bh0, c, 0, 0, 0); \
            c = __builtin_amdgcn_mfma_f32_16x16x32_bf16(qlo[tr][1], bh1, c, 0, 0, 0); \
            acc[tr][ct] = c;                                                  \
        }                                                                     \
    }

    MFMA_CHUNK(0, 6)
    __syncthreads();                                   // B2: kw_s visible

    // ---- theta + Sigma (from frags + kw_s), 4 shuffles ----
    {
        const float bq0 = bq[0], bk0 = bk[0];
#pragma unroll
        for (int tr = 0; tr < 2; ++tr) {
            const int row = rbase + tr * 16 + r16;
            float s = 0.f;
#pragma unroll
            for (int kk = 0; kk < 2; ++kk) {
                const float4 kwa = *(const float4*)(kw_s + kk * 32 + g4 * 8);
                const float4 kwb = *(const float4*)(kw_s + kk * 32 + g4 * 8 + 4);
                const float kwv[8] = {kwa.x, kwa.y, kwa.z, kwa.w, kwb.x, kwb.y, kwb.z, kwb.w};
#pragma unroll
                for (int e = 0; e < 8; ++e) {
                    const float qf = bf2f((unsigned short)qhi[tr][kk][e]) +
                                     bf2f((unsigned short)qlo[tr][kk][e]);
                    s += qf * kwv[e];
                }
            }
            s += __shfl_xor(s, 16);
            s += __shfl_xor(s, 32);
            if (g4 == 0) {
                sTh[row] = s - W1[row] * sPqk[row];
                sSq[row] = sPq[row] + bq0;
                sSk[row] = sPk[row] + bk0;
            }
        }
    }

    MFMA_CHUNK(6, 12)
    __syncthreads();                                   // B3: sTh/sSq/sSk visible

    // ---- GEMV: hdn = W2a @ theta, leaky(0.1), dot W2b ----
    {
        const int o = tid >> 1, ih = tid & 1;
        const float4* wrow = (const float4*)W2a + o * 64 + ih * 32;
        const float4* th4  = (const float4*)sTh + ih * 32;
        float h = 0.f;
#pragma unroll 8
        for (int c = 0; c < 32; ++c) {
            const float4 wv = wrow[c];
            const float4 tv = th4[c];
            h += wv.x * tv.x + wv.y * tv.y + wv.z * tv.z + wv.w * tv.w;
        }
        h += __shfl_xor(h, 1);
        float contrib = 0.f;
        if (ih == 0) {
            const float hl = (h >= 0.f) ? h : 0.1f * h;
            contrib = hl * W2b[o];
        }
#pragma unroll
        for (int m = 1; m < 64; m <<= 1) contrib += __shfl_xor(contrib, m);
        if (lane == 0) sRed[wid] = contrib;
    }

    MFMA_CHUNK(12, 16)
    __syncthreads();                                   // B4: sRed visible; MFMA done

    // ---- epilogue: logits, row softmax (unmasked denom), threshold, store ----
    const float th_sc = sRed[0] + sRed[1] + sRed[2] + sRed[3] +
                        sRed[4] + sRed[5] + sRed[6] + sRed[7];
    float skv[16];
#pragma unroll
    for (int ct = 0; ct < 16; ++ct) skv[ct] = sSk[ct * 16 + r16];

    float* og = out + (size_t)gidx * (LL * LL);
#pragma unroll
    for (int tr = 0; tr < 2; ++tr) {
#pragma unroll
        for (int r = 0; r < 4; ++r) {
            const int row = rbase + tr * 16 + g4 * 4 + r;   // C/D: row=(lane>>4)*4+reg
            const float sq = sSq[row];
            float lg[16];
            float mx = -INFINITY;
#pragma unroll
            for (int ct = 0; ct < 16; ++ct) {
                lg[ct] = acc[tr][ct][r] * sq * skv[ct];
                mx = fmaxf(mx, lg[ct]);
            }
            mx = fmaxf(mx, __shfl_xor(mx, 1));
            mx = fmaxf(mx, __shfl_xor(mx, 2));
            mx = fmaxf(mx, __shfl_xor(mx, 4));
            mx = fmaxf(mx, __shfl_xor(mx, 8));
            float sum = 0.f;
#pragma unroll
            for (int ct = 0; ct < 16; ++ct) {
                const float pe = __expf(lg[ct] - mx);
                sum += pe;                                  // unmasked denominator
                lg[ct] = (lg[ct] > th_sc) ? pe : 0.f;       // masked numerator
            }
            sum += __shfl_xor(sum, 1);
            sum += __shfl_xor(sum, 2);
            sum += __shfl_xor(sum, 4);
            sum += __shfl_xor(sum, 8);
            const float rinv = 1.0f / sum;
#pragma unroll
            for (int ct = 0; ct < 16; ++ct)
                og[row * LL + ct * 16 + r16] = lg[ct] * rinv;
        }
    }
}

extern "C" void kernel_launch(void* const* d_in, const int* in_sizes, int n_in,
                              void* d_out, int out_size, void* d_ws, size_t ws_size,
                              hipStream_t stream) {
    const float* q   = (const float*)d_in[0];
    const float* k   = (const float*)d_in[1];
    const float* Wq  = (const float*)d_in[2];
    const float* bq  = (const float*)d_in[3];
    const float* Wk  = (const float*)d_in[4];
    const float* bk  = (const float*)d_in[5];
    const float* W1  = (const float*)d_in[6];
    const float* W2a = (const float*)d_in[7];
    const float* W2b = (const float*)d_in[8];
    float* out = (float*)d_out;

    const int ngroup = in_sizes[0] / (LL * DD);        // 512
    const size_t lds_bytes = 65536 + 2120 * sizeof(float);  // 74016 B

    (void)hipFuncSetAttribute((const void*)fused_attn_mfma,
                              hipFuncAttributeMaxDynamicSharedMemorySize,
                              (int)lds_bytes);

    fused_attn_mfma<<<dim3(ngroup), dim3(512), lds_bytes, stream>>>(
        q, k, Wq, bq, Wk, bk, W1, W2a, W2b, out);
}

// Round 7
// 233.500 us; speedup vs baseline: 1.1642x; 1.1642x over previous
//
#include <hip/hip_runtime.h>
#include <math.h>

#define LL 256
#define DD 64

typedef __attribute__((ext_vector_type(8))) short bf16x8;
typedef __attribute__((ext_vector_type(4))) float f32x4;

static __device__ __forceinline__ unsigned short f2bf(float f) {
    union { float f; unsigned u; } v; v.f = f;
    unsigned r = v.u + 0x7fffu + ((v.u >> 16) & 1u);
    return (unsigned short)(r >> 16);
}
static __device__ __forceinline__ float bf2f(unsigned short h) {
    union { unsigned u; float f; } v; v.u = ((unsigned)h) << 16;
    return v.f;
}

// One block per (b,h,B) group. 512 threads = 8 waves; wave w owns rows [32w,32w+32).
// launch_bounds(512,2): VGPR cap 128 — (512,4) capped at 64 and spilled acc[] to
// scratch (+97MB WRITE, +73MB FETCH, dur 88->111us). Do not raise.
__launch_bounds__(512, 2)
__global__ void fused_attn_mfma(const float* __restrict__ q,
                                const float* __restrict__ k,
                                const float* __restrict__ Wq,
                                const float* __restrict__ bq,
                                const float* __restrict__ Wk,
                                const float* __restrict__ bk,
                                const float* __restrict__ W1,
                                const float* __restrict__ W2a,
                                const float* __restrict__ W2b,
                                float* __restrict__ out)
{
    extern __shared__ char smc[];
    unsigned short* kHi = (unsigned short*)smc;             // [256][64] bf16, swizzled
    unsigned short* kLo = (unsigned short*)(smc + 32768);
    float* sPq  = (float*)(smc + 65536);  // [256] q[i]·Wq
    float* sPk  = sPq + 256;              // [256] k[i]·Wk
    float* sPqk = sPk + 256;              // [256] q[i]·k[i]
    float* sTh  = sPqk + 256;             // [256] theta vector
    float* sSq  = sTh + 256;              // [256] Sigma_q
    float* sSk  = sSq + 256;              // [256] Sigma_k
    float* kwred= sSk + 256;              // [8][64]
    float* kw_s = kwred + 512;            // [64]
    float* sRed = kw_s + 64;              // [8]

    const int tid  = threadIdx.x;
    const int lane = tid & 63;
    const int wid  = tid >> 6;
    const int r16  = lane & 15;
    const int g4   = lane >> 4;
    const int rbase = wid * 32;
    const int gidx = blockIdx.x;
    const size_t gbase = (size_t)gidx * (LL * DD);
    const float* qg = q + gbase;
    const float4* q4 = (const float4*)qg;
    const float4* k4 = (const float4*)(k + gbase);

    // ---- A-operand (q) fragment loads, issued first ----
    float4 aq[2][2][2];
#pragma unroll
    for (int tr = 0; tr < 2; ++tr)
#pragma unroll
        for (int kk = 0; kk < 2; ++kk) {
            const float* p = qg + (rbase + tr * 16 + r16) * DD + kk * 32 + g4 * 8;
            aq[tr][kk][0] = ((const float4*)p)[0];
            aq[tr][kk][1] = ((const float4*)p)[1];
        }

    // ---- loop 1 (dim-major): stage k hi/lo to LDS + kw partials. NO shuffles ----
    const int dc = tid & 15;
    float kw0 = 0.f, kw1 = 0.f, kw2 = 0.f, kw3 = 0.f;
#pragma unroll
    for (int it = 0; it < 8; ++it) {
        const int f = it * 512 + tid;
        const int j = f >> 4;
        const float4 vk = k4[f];
        const int sw = (j & 7) << 4;
        const int boff = j * 128 + ((dc * 8) ^ sw);
        const unsigned short h0 = f2bf(vk.x), h1 = f2bf(vk.y),
                             h2 = f2bf(vk.z), h3 = f2bf(vk.w);
        uint2 hv, lv;
        hv.x = (unsigned)h0 | ((unsigned)h1 << 16);
        hv.y = (unsigned)h2 | ((unsigned)h3 << 16);
        const unsigned short l0 = f2bf(vk.x - bf2f(h0)), l1 = f2bf(vk.y - bf2f(h1)),
                             l2 = f2bf(vk.z - bf2f(h2)), l3 = f2bf(vk.w - bf2f(h3));
        lv.x = (unsigned)l0 | ((unsigned)l1 << 16);
        lv.y = (unsigned)l2 | ((unsigned)l3 << 16);
        *(uint2*)((char*)kHi + boff) = hv;
        *(uint2*)((char*)kLo + boff) = lv;

        const float w1j = W1[j];
        kw0 += w1j * vk.x; kw1 += w1j * vk.y; kw2 += w1j * vk.z; kw3 += w1j * vk.w;
    }

    // ---- loop 2 (row-pair): per-row dots accumulate in registers; 3 shuffles ----
    {
        const int j2 = tid >> 1, h2 = tid & 1;
        float pq = 0.f, pk = 0.f, pqk = 0.f;
#pragma unroll
        for (int it = 0; it < 8; ++it) {
            const int idx = j2 * 16 + h2 * 8 + it;
            const float4 vq = q4[idx];
            const float4 vk = k4[idx];
            const float4 wq4 = ((const float4*)Wq)[h2 * 8 + it];
            const float4 wk4 = ((const float4*)Wk)[h2 * 8 + it];
            pq  += vq.x * wq4.x + vq.y * wq4.y + vq.z * wq4.z + vq.w * wq4.w;
            pk  += vk.x * wk4.x + vk.y * wk4.y + vk.z * wk4.z + vk.w * wk4.w;
            pqk += vq.x * vk.x + vq.y * vk.y + vq.z * vk.z + vq.w * vk.w;
        }
        pq  += __shfl_xor(pq,  1);
        pk  += __shfl_xor(pk,  1);
        pqk += __shfl_xor(pqk, 1);
        if (h2 == 0) { sPq[j2] = pq; sPk[j2] = pk; sPqk[j2] = pqk; }
    }

    // ---- kw cross-lane reduce (8 shuffles, once) ----
    kw0 += __shfl_xor(kw0, 16); kw0 += __shfl_xor(kw0, 32);
    kw1 += __shfl_xor(kw1, 16); kw1 += __shfl_xor(kw1, 32);
    kw2 += __shfl_xor(kw2, 16); kw2 += __shfl_xor(kw2, 32);
    kw3 += __shfl_xor(kw3, 16); kw3 += __shfl_xor(kw3, 32);
    if (lane < 16) {
        float4 kv; kv.x = kw0; kv.y = kw1; kv.z = kw2; kv.w = kw3;
        ((float4*)kwred)[wid * 16 + lane] = kv;
    }

    // ---- convert A frags to bf16 hi/lo ----
    bf16x8 qhi[2][2], qlo[2][2];
#pragma unroll
    for (int tr = 0; tr < 2; ++tr)
#pragma unroll
        for (int kk = 0; kk < 2; ++kk) {
            const float fv[8] = {aq[tr][kk][0].x, aq[tr][kk][0].y, aq[tr][kk][0].z, aq[tr][kk][0].w,
                                 aq[tr][kk][1].x, aq[tr][kk][1].y, aq[tr][kk][1].z, aq[tr][kk][1].w};
#pragma unroll
            for (int e = 0; e < 8; ++e) {
                const unsigned short h = f2bf(fv[e]);
                qhi[tr][kk][e] = (short)h;
                qlo[tr][kk][e] = (short)f2bf(fv[e] - bf2f(h));
            }
        }

    __syncthreads();                                   // B1: staging + kwred + sP* done

    if (tid < 64) {
        float s = 0.f;
#pragma unroll
        for (int w = 0; w < 8; ++w) s += kwred[w * 64 + tid];
        kw_s[tid] = s;
    }

    // ---- MFMA accumulators; chunks interleaved with small phases ----
    f32x4 acc[2][16];
#pragma unroll
    for (int tr = 0; tr < 2; ++tr)
#pragma unroll
        for (int ct = 0; ct < 16; ++ct)
            acc[tr][ct] = (f32x4){0.f, 0.f, 0.f, 0.f};

#define MFMA_CHUNK(CT0, CT1)                                                  \
    _Pragma("unroll")                                                         \
    for (int ct = (CT0); ct < (CT1); ++ct) {                                  \
        const int rowk = ct * 16 + r16;                                       \
        const int sw = (rowk & 7) << 4;                                       \
        const char* ph = (const char*)kHi + rowk * 128;                       \
        const char* pl = (const char*)kLo + rowk * 128;                       \
        const bf16x8 bh0 = *(const bf16x8*)(ph + ((g4 * 16) ^ sw));           \
        const bf16x8 bh1 = *(const bf16x8*)(ph + ((64 + g4 * 16) ^ sw));      \
        const bf16x8 bl0 = *(const bf16x8*)(pl + ((g4 * 16) ^ sw));           \
        const bf16x8 bl1 = *(const bf16x8*)(pl + ((64 + g4 * 16) ^ sw));      \
        _Pragma("unroll")                                                     \
        for (int tr = 0; tr < 2; ++tr) {                                      \
            f32x4 c = acc[tr][ct];                                            \
            c = __builtin_amdgcn_mfma_f32_16x16x32_bf16(qhi[tr][0], bh0, c, 0, 0, 0); \
            c = __builtin_amdgcn_mfma_f32_16x16x32_bf16(qhi[tr][1], bh1, c, 0, 0, 0); \
            c = __builtin_amdgcn_mfma_f32_16x16x32_bf16(qhi[tr][0], bl0, c, 0, 0, 0); \
            c = __builtin_amdgcn_mfma_f32_16x16x32_bf16(qhi[tr][1], bl1, c, 0, 0, 0); \
            c = __builtin_amdgcn_mfma_f32_16x16x32_bf16(qlo[tr][0], bh0, c, 0, 0, 0); \
            c = __builtin_amdgcn_mfma_f32_16x16x32_bf16(qlo[tr][1], bh1, c, 0, 0, 0); \
            acc[tr][ct] = c;                                                  \
        }                                                                     \
    }

    MFMA_CHUNK(0, 6)
    __syncthreads();                                   // B2: kw_s visible

    // ---- theta + Sigma (from frags + kw_s), 4 shuffles ----
    {
        const float bq0 = bq[0], bk0 = bk[0];
#pragma unroll
        for (int tr = 0; tr < 2; ++tr) {
            const int row = rbase + tr * 16 + r16;
            float s = 0.f;
#pragma unroll
            for (int kk = 0; kk < 2; ++kk) {
                const float4 kwa = *(const float4*)(kw_s + kk * 32 + g4 * 8);
                const float4 kwb = *(const float4*)(kw_s + kk * 32 + g4 * 8 + 4);
                const float kwv[8] = {kwa.x, kwa.y, kwa.z, kwa.w, kwb.x, kwb.y, kwb.z, kwb.w};
#pragma unroll
                for (int e = 0; e < 8; ++e) {
                    const float qf = bf2f((unsigned short)qhi[tr][kk][e]) +
                                     bf2f((unsigned short)qlo[tr][kk][e]);
                    s += qf * kwv[e];
                }
            }
            s += __shfl_xor(s, 16);
            s += __shfl_xor(s, 32);
            if (g4 == 0) {
                sTh[row] = s - W1[row] * sPqk[row];
                sSq[row] = sPq[row] + bq0;
                sSk[row] = sPk[row] + bk0;
            }
        }
    }

    MFMA_CHUNK(6, 12)
    __syncthreads();                                   // B3: sTh/sSq/sSk visible

    // ---- GEMV: hdn = W2a @ theta, leaky(0.1), dot W2b ----
    {
        const int o = tid >> 1, ih = tid & 1;
        const float4* wrow = (const float4*)W2a + o * 64 + ih * 32;
        const float4* th4  = (const float4*)sTh + ih * 32;
        float h = 0.f;
#pragma unroll 8
        for (int c = 0; c < 32; ++c) {
            const float4 wv = wrow[c];
            const float4 tv = th4[c];
            h += wv.x * tv.x + wv.y * tv.y + wv.z * tv.z + wv.w * tv.w;
        }
        h += __shfl_xor(h, 1);
        float contrib = 0.f;
        if (ih == 0) {
            const float hl = (h >= 0.f) ? h : 0.1f * h;
            contrib = hl * W2b[o];
        }
#pragma unroll
        for (int m = 1; m < 64; m <<= 1) contrib += __shfl_xor(contrib, m);
        if (lane == 0) sRed[wid] = contrib;
    }

    MFMA_CHUNK(12, 16)
    __syncthreads();                                   // B4: sRed visible; MFMA done

    // ---- epilogue: logits, row softmax (unmasked denom), threshold, store ----
    const float th_sc = sRed[0] + sRed[1] + sRed[2] + sRed[3] +
                        sRed[4] + sRed[5] + sRed[6] + sRed[7];
    float skv[16];
#pragma unroll
    for (int ct = 0; ct < 16; ++ct) skv[ct] = sSk[ct * 16 + r16];

    float* og = out + (size_t)gidx * (LL * LL);
#pragma unroll
    for (int tr = 0; tr < 2; ++tr) {
#pragma unroll
        for (int r = 0; r < 4; ++r) {
            const int row = rbase + tr * 16 + g4 * 4 + r;   // C/D: row=(lane>>4)*4+reg
            const float sq = sSq[row];
            float lg[16];
            float mx = -INFINITY;
#pragma unroll
            for (int ct = 0; ct < 16; ++ct) {
                lg[ct] = acc[tr][ct][r] * sq * skv[ct];
                mx = fmaxf(mx, lg[ct]);
            }
            mx = fmaxf(mx, __shfl_xor(mx, 1));
            mx = fmaxf(mx, __shfl_xor(mx, 2));
            mx = fmaxf(mx, __shfl_xor(mx, 4));
            mx = fmaxf(mx, __shfl_xor(mx, 8));
            float sum = 0.f;
#pragma unroll
            for (int ct = 0; ct < 16; ++ct) {
                const float pe = __expf(lg[ct] - mx);
                sum += pe;                                  // unmasked denominator
                lg[ct] = (lg[ct] > th_sc) ? pe : 0.f;       // masked numerator
            }
            sum += __shfl_xor(sum, 1);
            sum += __shfl_xor(sum, 2);
            sum += __shfl_xor(sum, 4);
            sum += __shfl_xor(sum, 8);
            const float rinv = 1.0f / sum;
#pragma unroll
            for (int ct = 0; ct < 16; ++ct)
                og[row * LL + ct * 16 + r16] = lg[ct] * rinv;
        }
    }
}

extern "C" void kernel_launch(void* const* d_in, const int* in_sizes, int n_in,
                              void* d_out, int out_size, void* d_ws, size_t ws_size,
                              hipStream_t stream) {
    const float* q   = (const float*)d_in[0];
    const float* k   = (const float*)d_in[1];
    const float* Wq  = (const float*)d_in[2];
    const float* bq  = (const float*)d_in[3];
    const float* Wk  = (const float*)d_in[4];
    const float* bk  = (const float*)d_in[5];
    const float* W1  = (const float*)d_in[6];
    const float* W2a = (const float*)d_in[7];
    const float* W2b = (const float*)d_in[8];
    float* out = (float*)d_out;

    const int ngroup = in_sizes[0] / (LL * DD);        // 512
    const size_t lds_bytes = 65536 + 2120 * sizeof(float);  // 74016 B

    (void)hipFuncSetAttribute((const void*)fused_attn_mfma,
                              hipFuncAttributeMaxDynamicSharedMemorySize,
                              (int)lds_bytes);

    fused_attn_mfma<<<dim3(ngroup), dim3(512), lds_bytes, stream>>>(
        q, k, Wq, bq, Wk, bk, W1, W2a, W2b, out);
}